// Round 1
// baseline (483.425 us; speedup 1.0000x reference)
//
#include <hip/hip_runtime.h>

#define NN 100000
#define NE 800000
#define CH 128
#define CH4 32

// ---- workspace layout (bytes) ----
#define OFF_DEG      0u                         // int[2N]
#define OFF_INV      800000u                    // float[2N]
#define OFF_OFFS     1600000u                   // int[2N+1]
#define OFF_CURS     2400016u                   // int[2N]
#define OFF_BSUMS    3200016u                   // int[256]
#define OFF_BBASE    3201040u                   // int[257]
#define OFF_CSRC     3202080u                   // int[2E]
#define OFF_CSRW     9602080u                   // float[2E]
#define OFF_AGGI     16002080u                  // float[N*CH]
#define OFF_AGGO     67202080u                  // float[N*CH]

#define SCAN_BLOCKS 196   // ceil(2N/1024)

__global__ void k_deg(const int* __restrict__ ei, int* __restrict__ deg) {
    int e = blockIdx.x * blockDim.x + threadIdx.x;
    if (e < NE) {
        atomicAdd(&deg[ei[e]], 1);            // row occurrences
        atomicAdd(&deg[NN + ei[NE + e]], 1);  // col occurrences
    }
}

// per-block (1024 elems) sums + rsqrt
__global__ void k_scan1(const int* __restrict__ deg, float* __restrict__ inv,
                        int* __restrict__ bsums) {
    __shared__ int sdata[256];
    int base = blockIdx.x * 1024;
    int tsum = 0;
    for (int j = 0; j < 4; ++j) {
        int i = base + threadIdx.x * 4 + j;
        if (i < 2 * NN) {
            int d = deg[i];
            inv[i] = (d > 0) ? rsqrtf((float)d) : 0.0f;
            tsum += d;
        }
    }
    sdata[threadIdx.x] = tsum;
    __syncthreads();
    for (int s = 128; s > 0; s >>= 1) {
        if (threadIdx.x < s) sdata[threadIdx.x] += sdata[threadIdx.x + s];
        __syncthreads();
    }
    if (threadIdx.x == 0) bsums[blockIdx.x] = sdata[0];
}

__global__ void k_scan2(const int* __restrict__ bsums, int* __restrict__ bbase, int nb) {
    if (threadIdx.x == 0) {
        int run = 0;
        for (int b = 0; b < nb; ++b) { bbase[b] = run; run += bsums[b]; }
        bbase[nb] = run;
    }
}

__global__ void k_scan3(const int* __restrict__ deg, const int* __restrict__ bbase,
                        int* __restrict__ offsets, int* __restrict__ cursor) {
    __shared__ int sdata[256];
    int base = blockIdx.x * 1024;
    int vals[4];
    int tsum = 0;
    for (int j = 0; j < 4; ++j) {
        int i = base + threadIdx.x * 4 + j;
        vals[j] = (i < 2 * NN) ? deg[i] : 0;
        tsum += vals[j];
    }
    sdata[threadIdx.x] = tsum;
    __syncthreads();
    // Hillis-Steele inclusive scan
    for (int s = 1; s < 256; s <<= 1) {
        int v = (threadIdx.x >= (unsigned)s) ? sdata[threadIdx.x - s] : 0;
        __syncthreads();
        sdata[threadIdx.x] += v;
        __syncthreads();
    }
    int excl = bbase[blockIdx.x] + ((threadIdx.x > 0) ? sdata[threadIdx.x - 1] : 0);
    for (int j = 0; j < 4; ++j) {
        int i = base + threadIdx.x * 4 + j;
        if (i < 2 * NN) {
            offsets[i] = excl;
            cursor[i]  = excl;
            excl += vals[j];
        }
    }
    if (blockIdx.x == 0 && threadIdx.x == 0) offsets[2 * NN] = 2 * NE;
}

__global__ void k_fill(const int* __restrict__ ei, const float* __restrict__ inv,
                       int* __restrict__ cursor, int* __restrict__ csr_src,
                       float* __restrict__ csr_w) {
    int e = blockIdx.x * blockDim.x + threadIdx.x;
    if (e >= NE) return;
    int r = ei[e];
    int c = ei[NE + e];
    float w = 0.5f * inv[r] * inv[NN + c];   // 0.5 = ALPHA fold
    int p1 = atomicAdd(&cursor[r], 1);       // keyed by row -> in-aggregation
    csr_src[p1] = c;
    csr_w[p1] = w;
    int p2 = atomicAdd(&cursor[NN + c], 1);  // keyed by col -> out-aggregation
    csr_src[p2] = r;
    csr_w[p2] = w;
}

// 8 nodes per 256-thread block; 32 lanes (float4) per node
__global__ __launch_bounds__(256) void k_gather(
    const float4* __restrict__ x4, const int* __restrict__ offsets,
    const int* __restrict__ csr_src, const float* __restrict__ csr_w,
    float4* __restrict__ agg_in, float4* __restrict__ agg_out) {
    int lane = threadIdx.x & 31;
    int slot = threadIdx.x >> 5;
    int n = blockIdx.x * 8 + slot;
    if (n >= NN) return;

    float4 ai = {0.f, 0.f, 0.f, 0.f};
    int s0 = offsets[n], s1 = offsets[n + 1];
    for (int e = s0; e < s1; ++e) {
        int src = csr_src[e];
        float w = csr_w[e];
        float4 v = x4[src * CH4 + lane];
        ai.x += w * v.x; ai.y += w * v.y; ai.z += w * v.z; ai.w += w * v.w;
    }
    agg_in[n * CH4 + lane] = ai;

    float4 ao = {0.f, 0.f, 0.f, 0.f};
    int t0 = offsets[NN + n], t1 = offsets[NN + n + 1];
    for (int e = t0; e < t1; ++e) {
        int src = csr_src[e];
        float w = csr_w[e];
        float4 v = x4[src * CH4 + lane];
        ao.x += w * v.x; ao.y += w * v.y; ao.z += w * v.z; ao.w += w * v.w;
    }
    agg_out[n * CH4 + lane] = ao;
}

// out = agg_in @ W_ds + agg_out @ W_sd + 0.5*(b_ds + b_sd)
// one thread per row, 64 output cols (blockIdx.y selects col-half).
// W reads are wave-uniform -> scalar loads, FMAs take SGPR operand.
__global__ __launch_bounds__(256) void k_gemm(
    const float4* __restrict__ agg_in, const float4* __restrict__ agg_out,
    const float4* __restrict__ Wds4, const float4* __restrict__ Wsd4,
    const float4* __restrict__ bds4, const float4* __restrict__ bsd4,
    float4* __restrict__ out4) {
    const int ch = blockIdx.y;            // 0 or 1: which 64-col half
    const int r = blockIdx.x * 256 + threadIdx.x;
    if (r >= NN) return;

    float4 acc[16];
#pragma unroll
    for (int j = 0; j < 16; ++j) {
        float4 bd = bds4[ch * 16 + j];
        float4 bs = bsd4[ch * 16 + j];
        acc[j].x = 0.5f * (bd.x + bs.x);
        acc[j].y = 0.5f * (bd.y + bs.y);
        acc[j].z = 0.5f * (bd.z + bs.z);
        acc[j].w = 0.5f * (bd.w + bs.w);
    }

#pragma unroll 2
    for (int k4 = 0; k4 < 32; ++k4) {
        float4 ai4 = agg_in[r * 32 + k4];
        float4 ao4 = agg_out[r * 32 + k4];
#pragma unroll
        for (int kk = 0; kk < 4; ++kk) {
            float ai = (&ai4.x)[kk];
            float ao = (&ao4.x)[kk];
            int k = k4 * 4 + kk;
#pragma unroll
            for (int j = 0; j < 16; ++j) {
                float4 wd = Wds4[k * 32 + ch * 16 + j];
                float4 ws = Wsd4[k * 32 + ch * 16 + j];
                acc[j].x += ai * wd.x + ao * ws.x;
                acc[j].y += ai * wd.y + ao * ws.y;
                acc[j].z += ai * wd.z + ao * ws.z;
                acc[j].w += ai * wd.w + ao * ws.w;
            }
        }
    }

#pragma unroll
    for (int j = 0; j < 16; ++j) out4[r * 32 + ch * 16 + j] = acc[j];
}

extern "C" void kernel_launch(void* const* d_in, const int* in_sizes, int n_in,
                              void* d_out, int out_size, void* d_ws, size_t ws_size,
                              hipStream_t stream) {
    const float* x   = (const float*)d_in[0];
    const int* ei    = (const int*)d_in[1];
    const float* Wsd = (const float*)d_in[2];
    const float* bsd = (const float*)d_in[3];
    const float* Wds = (const float*)d_in[4];
    const float* bds = (const float*)d_in[5];

    char* ws = (char*)d_ws;
    int*   deg     = (int*)(ws + OFF_DEG);
    float* inv     = (float*)(ws + OFF_INV);
    int*   offsets = (int*)(ws + OFF_OFFS);
    int*   cursor  = (int*)(ws + OFF_CURS);
    int*   bsums   = (int*)(ws + OFF_BSUMS);
    int*   bbase   = (int*)(ws + OFF_BBASE);
    int*   csr_src = (int*)(ws + OFF_CSRC);
    float* csr_w   = (float*)(ws + OFF_CSRW);
    float* agg_in  = (float*)(ws + OFF_AGGI);
    float* agg_out = (float*)(ws + OFF_AGGO);

    hipMemsetAsync(deg, 0, 2 * NN * sizeof(int), stream);

    k_deg<<<(NE + 255) / 256, 256, 0, stream>>>(ei, deg);
    k_scan1<<<SCAN_BLOCKS, 256, 0, stream>>>(deg, inv, bsums);
    k_scan2<<<1, 64, 0, stream>>>(bsums, bbase, SCAN_BLOCKS);
    k_scan3<<<SCAN_BLOCKS, 256, 0, stream>>>(deg, bbase, offsets, cursor);
    k_fill<<<(NE + 255) / 256, 256, 0, stream>>>(ei, inv, cursor, csr_src, csr_w);
    k_gather<<<(NN + 7) / 8, 256, 0, stream>>>((const float4*)x, offsets, csr_src, csr_w,
                                               (float4*)agg_in, (float4*)agg_out);
    k_gemm<<<dim3((NN + 255) / 256, 2), 256, 0, stream>>>(
        (const float4*)agg_in, (const float4*)agg_out,
        (const float4*)Wds, (const float4*)Wsd,
        (const float4*)bds, (const float4*)bsd,
        (float4*)d_out);
}

// Round 2
// 379.002 us; speedup vs baseline: 1.2755x; 1.2755x over previous
//
#include <hip/hip_runtime.h>

#define NN 100000
#define NE 800000

// ---- workspace layout (bytes) ----
#define OFF_DEG      0u           // int[2N]
#define OFF_INV      800000u      // float[2N]
#define OFF_OFFS     1600000u     // int[2N+1]
#define OFF_CURS     2400016u     // int[2N]
#define OFF_BSUMS    3200016u     // int[256]
#define OFF_BBASE    3201040u     // int[260]
#define OFF_CSRC     3202080u     // int[2E]
#define OFF_CSRW     9602080u     // float[2E]
#define OFF_XB       16002080u    // bf16[N*128]
#define OFF_AGG      41602080u    // bf16[N*256]  (cols 0..127 = agg_in, 128..255 = agg_out)
#define OFF_WT       92802080u    // bf16[128*256] W^T concat: WT[c][k], k<128 -> W_ds, else W_sd
#define OFF_BIAS     92867616u    // float[128]   0.5*(b_ds+b_sd)

#define SCAN_BLOCKS 196   // ceil(2N/1024)

typedef short short8 __attribute__((ext_vector_type(8)));
typedef float f32x4 __attribute__((ext_vector_type(4)));

__device__ __forceinline__ unsigned short f2bf(float f) {
    unsigned u = __float_as_uint(f);
    u = (u + 0x7FFFu + ((u >> 16) & 1u)) >> 16;   // RNE
    return (unsigned short)u;
}
__device__ __forceinline__ float b2f(unsigned short h) {
    return __uint_as_float(((unsigned)h) << 16);
}

__global__ void k_deg(const int* __restrict__ ei, int* __restrict__ deg) {
    int e = blockIdx.x * blockDim.x + threadIdx.x;
    if (e < NE) {
        atomicAdd(&deg[ei[e]], 1);            // row occurrences
        atomicAdd(&deg[NN + ei[NE + e]], 1);  // col occurrences
    }
}

__global__ void k_scan1(const int* __restrict__ deg, float* __restrict__ inv,
                        int* __restrict__ bsums) {
    __shared__ int sdata[256];
    int base = blockIdx.x * 1024;
    int tsum = 0;
    for (int j = 0; j < 4; ++j) {
        int i = base + threadIdx.x * 4 + j;
        if (i < 2 * NN) {
            int d = deg[i];
            inv[i] = (d > 0) ? rsqrtf((float)d) : 0.0f;
            tsum += d;
        }
    }
    sdata[threadIdx.x] = tsum;
    __syncthreads();
    for (int s = 128; s > 0; s >>= 1) {
        if (threadIdx.x < s) sdata[threadIdx.x] += sdata[threadIdx.x + s];
        __syncthreads();
    }
    if (threadIdx.x == 0) bsums[blockIdx.x] = sdata[0];
}

__global__ void k_scan2(const int* __restrict__ bsums, int* __restrict__ bbase, int nb) {
    if (threadIdx.x == 0) {
        int run = 0;
        for (int b = 0; b < nb; ++b) { bbase[b] = run; run += bsums[b]; }
        bbase[nb] = run;
    }
}

__global__ void k_scan3(const int* __restrict__ deg, const int* __restrict__ bbase,
                        int* __restrict__ offsets, int* __restrict__ cursor) {
    __shared__ int sdata[256];
    int base = blockIdx.x * 1024;
    int vals[4];
    int tsum = 0;
    for (int j = 0; j < 4; ++j) {
        int i = base + threadIdx.x * 4 + j;
        vals[j] = (i < 2 * NN) ? deg[i] : 0;
        tsum += vals[j];
    }
    sdata[threadIdx.x] = tsum;
    __syncthreads();
    for (int s = 1; s < 256; s <<= 1) {
        int v = (threadIdx.x >= (unsigned)s) ? sdata[threadIdx.x - s] : 0;
        __syncthreads();
        sdata[threadIdx.x] += v;
        __syncthreads();
    }
    int excl = bbase[blockIdx.x] + ((threadIdx.x > 0) ? sdata[threadIdx.x - 1] : 0);
    for (int j = 0; j < 4; ++j) {
        int i = base + threadIdx.x * 4 + j;
        if (i < 2 * NN) {
            offsets[i] = excl;
            cursor[i]  = excl;
            excl += vals[j];
        }
    }
    if (blockIdx.x == 0 && threadIdx.x == 0) offsets[2 * NN] = 2 * NE;
}

__global__ void k_fill(const int* __restrict__ ei, const float* __restrict__ inv,
                       int* __restrict__ cursor, int* __restrict__ csr_src,
                       float* __restrict__ csr_w) {
    int e = blockIdx.x * blockDim.x + threadIdx.x;
    if (e >= NE) return;
    int r = ei[e];
    int c = ei[NE + e];
    float w = 0.5f * inv[r] * inv[NN + c];   // ALPHA fold (ALPHA = 1-ALPHA = 0.5)
    int p1 = atomicAdd(&cursor[r], 1);       // keyed by row -> in-aggregation sources
    csr_src[p1] = c;
    csr_w[p1] = w;
    int p2 = atomicAdd(&cursor[NN + c], 1);  // keyed by col -> out-aggregation sources
    csr_src[p2] = r;
    csr_w[p2] = w;
}

// x fp32 -> bf16
__global__ __launch_bounds__(256) void k_cvt_x(const float4* __restrict__ x4,
                                               ushort4* __restrict__ xb4) {
    int i = blockIdx.x * blockDim.x + threadIdx.x;
    if (i >= NN * 32) return;
    float4 v = x4[i];
    ushort4 o;
    o.x = f2bf(v.x); o.y = f2bf(v.y); o.z = f2bf(v.z); o.w = f2bf(v.w);
    xb4[i] = o;
}

// Build WT[c][k] (bf16, c in [0,128), k in [0,256)) and bias
__global__ void k_prep_w(const float* __restrict__ Wds, const float* __restrict__ Wsd,
                         const float* __restrict__ bds, const float* __restrict__ bsd,
                         unsigned short* __restrict__ wt, float* __restrict__ bias) {
    int id = blockIdx.x * blockDim.x + threadIdx.x;   // 32768 total
    if (id >= 128 * 256) return;
    int c = id & 127;
    int k = id >> 7;
    float v = (k < 128) ? Wds[k * 128 + c] : Wsd[(k - 128) * 128 + c];
    wt[c * 256 + k] = f2bf(v);
    if (k == 0) bias[c] = 0.5f * (bds[c] + bsd[c]);
}

// 8 nodes per 256-thread block; 32 lanes (4 bf16 channels each) per node
__global__ __launch_bounds__(256) void k_gather(
    const ushort4* __restrict__ xb4, const int* __restrict__ offsets,
    const int* __restrict__ csr_src, const float* __restrict__ csr_w,
    ushort4* __restrict__ agg4) {
    int lane = threadIdx.x & 31;
    int slot = threadIdx.x >> 5;
    int n = blockIdx.x * 8 + slot;
    if (n >= NN) return;

    float4 ai = {0.f, 0.f, 0.f, 0.f};
    int s0 = offsets[n], s1 = offsets[n + 1];
    for (int e = s0; e < s1; ++e) {
        int src = csr_src[e];
        float w = csr_w[e];
        ushort4 v = xb4[src * 32 + lane];
        ai.x += w * b2f(v.x); ai.y += w * b2f(v.y);
        ai.z += w * b2f(v.z); ai.w += w * b2f(v.w);
    }
    ushort4 oi; oi.x = f2bf(ai.x); oi.y = f2bf(ai.y); oi.z = f2bf(ai.z); oi.w = f2bf(ai.w);
    agg4[n * 64 + lane] = oi;

    float4 ao = {0.f, 0.f, 0.f, 0.f};
    int t0 = offsets[NN + n], t1 = offsets[NN + n + 1];
    for (int e = t0; e < t1; ++e) {
        int src = csr_src[e];
        float w = csr_w[e];
        ushort4 v = xb4[src * 32 + lane];
        ao.x += w * b2f(v.x); ao.y += w * b2f(v.y);
        ao.z += w * b2f(v.z); ao.w += w * b2f(v.w);
    }
    ushort4 oo; oo.x = f2bf(ao.x); oo.y = f2bf(ao.y); oo.z = f2bf(ao.z); oo.w = f2bf(ao.w);
    agg4[n * 64 + 32 + lane] = oo;
}

// out[N][128] = agg[N][256](bf16) @ WT^T (K=256) + bias
// 4 waves/block, each wave: 16 rows x 128 cols via 8 col-tiles of 16x16x32 MFMA
__global__ __launch_bounds__(256) void k_gemm_mfma(
    const unsigned short* __restrict__ agg, const unsigned short* __restrict__ wt,
    const float* __restrict__ bias, float* __restrict__ out) {
    const int wave = threadIdx.x >> 6;
    const int lane = threadIdx.x & 63;
    const int row0 = blockIdx.x * 64 + wave * 16;
    const int fr = lane & 15;        // A-row / B-col within tile
    const int kg = (lane >> 4) * 8;  // k sub-base for this lane group

    int arow = row0 + fr;
    if (arow >= NN) arow = 0;        // clamp (stores are masked)
    const unsigned short* aptr = agg + arow * 256 + kg;

    f32x4 acc[8] = {};

#pragma unroll
    for (int s = 0; s < 8; ++s) {
        short8 afrag = *(const short8*)(aptr + s * 32);
#pragma unroll
        for (int t = 0; t < 8; ++t) {
            short8 bfrag = *(const short8*)(wt + (t * 16 + fr) * 256 + s * 32 + kg);
            acc[t] = __builtin_amdgcn_mfma_f32_16x16x32_bf16(afrag, bfrag, acc[t], 0, 0, 0);
        }
    }

    const int orow0 = row0 + (lane >> 4) * 4;
#pragma unroll
    for (int i = 0; i < 4; ++i) {
        int orow = orow0 + i;
        if (orow < NN) {
#pragma unroll
            for (int t = 0; t < 8; ++t) {
                int col = t * 16 + fr;
                out[orow * 128 + col] = acc[t][i] + bias[col];
            }
        }
    }
}

extern "C" void kernel_launch(void* const* d_in, const int* in_sizes, int n_in,
                              void* d_out, int out_size, void* d_ws, size_t ws_size,
                              hipStream_t stream) {
    const float* x   = (const float*)d_in[0];
    const int* ei    = (const int*)d_in[1];
    const float* Wsd = (const float*)d_in[2];
    const float* bsd = (const float*)d_in[3];
    const float* Wds = (const float*)d_in[4];
    const float* bds = (const float*)d_in[5];

    char* ws = (char*)d_ws;
    int*   deg     = (int*)(ws + OFF_DEG);
    float* inv     = (float*)(ws + OFF_INV);
    int*   offsets = (int*)(ws + OFF_OFFS);
    int*   cursor  = (int*)(ws + OFF_CURS);
    int*   bsums   = (int*)(ws + OFF_BSUMS);
    int*   bbase   = (int*)(ws + OFF_BBASE);
    int*   csr_src = (int*)(ws + OFF_CSRC);
    float* csr_w   = (float*)(ws + OFF_CSRW);
    unsigned short* xb  = (unsigned short*)(ws + OFF_XB);
    unsigned short* agg = (unsigned short*)(ws + OFF_AGG);
    unsigned short* wt  = (unsigned short*)(ws + OFF_WT);
    float* bias    = (float*)(ws + OFF_BIAS);

    hipMemsetAsync(deg, 0, 2 * NN * sizeof(int), stream);

    k_deg<<<(NE + 255) / 256, 256, 0, stream>>>(ei, deg);
    k_cvt_x<<<(NN * 32 + 255) / 256, 256, 0, stream>>>((const float4*)x, (ushort4*)xb);
    k_prep_w<<<(128 * 256 + 255) / 256, 256, 0, stream>>>(Wds, Wsd, bds, bsd, wt, bias);
    k_scan1<<<SCAN_BLOCKS, 256, 0, stream>>>(deg, inv, bsums);
    k_scan2<<<1, 64, 0, stream>>>(bsums, bbase, SCAN_BLOCKS);
    k_scan3<<<SCAN_BLOCKS, 256, 0, stream>>>(deg, bbase, offsets, cursor);
    k_fill<<<(NE + 255) / 256, 256, 0, stream>>>(ei, inv, cursor, csr_src, csr_w);
    k_gather<<<(NN + 7) / 8, 256, 0, stream>>>((const ushort4*)xb, offsets, csr_src, csr_w,
                                               (ushort4*)agg);
    k_gemm_mfma<<<(NN + 63) / 64, 256, 0, stream>>>(agg, wt, bias, (float*)d_out);
}